// Round 2
// baseline (898.488 us; speedup 1.0000x reference)
//
#include <hip/hip_runtime.h>

// RickerCWT: out[b,s,t] = sum_k x[b, t+k-PAD] * W[s,k]  (zero-padded borders)
// B=128, T=4096, S=64, K=543 (odd, PAD=271). Cross-correlation (JAX conv).
//
// Round 2: all weight accesses routed through LDS with 544-float padded rows so
// every float4 access (LDS and global) is provably 16B-aligned — round 1's
// misaligned *(float4*)&W[s*543+k] UB is gone. No VMEM in the K-loop.

#define BATCH 128
#define TLEN  4096
#define NSC   64
#define KLEN  543
#define PADL  271              // KLEN/2
#define BLOCK 256
#define VT    8                // t-outputs per thread
#define TTILE (BLOCK * VT)     // 2048
#define XLEN  (TTILE + KLEN - 1)  // 2590
#define SG    8                // scales per block (staged in LDS)
#define SI    4                // scales per register pass
#define WROW  544              // padded W row (16B-aligned rows: 544 % 4 == 0)

__global__ __launch_bounds__(BLOCK)
void ricker_cwt_f32(const float* __restrict__ x,
                    const float* __restrict__ W,
                    float* __restrict__ out)
{
    __shared__ __align__(16) float xs[XLEN + 2];        // 2592 floats
    __shared__ __align__(16) float wsh[SG * WROW];      // 4352 floats

    const int tid    = threadIdx.x;
    const int tTile  = blockIdx.x;   // 0..1
    const int sGroup = blockIdx.y;   // 0..7
    const int b      = blockIdx.z;   // 0..127
    const int tStart = tTile * TTILE;

    // ---- stage input tile (zero-padded halo), coalesced ----
    const float* xrow = x + (size_t)b * TLEN;
    for (int i = tid; i < XLEN; i += BLOCK) {
        int g = tStart - PADL + i;
        xs[i] = (g >= 0 && g < TLEN) ? xrow[g] : 0.0f;
    }

    // ---- stage this block's 8 W rows into LDS, padded to WROW ----
    const float* wg = W + (size_t)sGroup * SG * KLEN;
    #pragma unroll
    for (int r = 0; r < SG; ++r) {
        for (int c = tid; c < KLEN; c += BLOCK) {
            wsh[r * WROW + c] = wg[r * KLEN + c];
        }
    }
    __syncthreads();

    const int xoff = tid * VT;           // 32B-aligned LDS window base
    const int t0   = tStart + xoff;

    for (int sp = 0; sp < SG; sp += SI) {
        const float* w0 = &wsh[(sp + 0) * WROW];
        const float* w1 = &wsh[(sp + 1) * WROW];
        const float* w2 = &wsh[(sp + 2) * WROW];
        const float* w3 = &wsh[(sp + 3) * WROW];

        float acc0[VT], acc1[VT], acc2[VT], acc3[VT];
        #pragma unroll
        for (int j = 0; j < VT; ++j) {
            acc0[j] = 0.0f; acc1[j] = 0.0f; acc2[j] = 0.0f; acc3[j] = 0.0f;
        }

        // main loop: 4 taps x 8 outputs x 4 scales per iteration (128 FMA)
        for (int k = 0; k < KLEN - 3; k += 4) {
            float4 xa = *(const float4*)&xs[xoff + k];       // aligned: mult of 4
            float4 xb = *(const float4*)&xs[xoff + k + 4];
            float4 xc = *(const float4*)&xs[xoff + k + 8];
            float xr[12] = {xa.x, xa.y, xa.z, xa.w,
                            xb.x, xb.y, xb.z, xb.w,
                            xc.x, xc.y, xc.z, xc.w};
            float4 wa = *(const float4*)&w0[k];              // aligned: 544*r + 4k
            float4 wb = *(const float4*)&w1[k];
            float4 wc = *(const float4*)&w2[k];
            float4 wd = *(const float4*)&w3[k];
            #pragma unroll
            for (int j = 0; j < VT; ++j) {
                acc0[j] += xr[j]   * wa.x;
                acc0[j] += xr[j+1] * wa.y;
                acc0[j] += xr[j+2] * wa.z;
                acc0[j] += xr[j+3] * wa.w;
                acc1[j] += xr[j]   * wb.x;
                acc1[j] += xr[j+1] * wb.y;
                acc1[j] += xr[j+2] * wb.z;
                acc1[j] += xr[j+3] * wb.w;
                acc2[j] += xr[j]   * wc.x;
                acc2[j] += xr[j+1] * wc.y;
                acc2[j] += xr[j+2] * wc.z;
                acc2[j] += xr[j+3] * wc.w;
                acc3[j] += xr[j]   * wd.x;
                acc3[j] += xr[j+1] * wd.y;
                acc3[j] += xr[j+2] * wd.z;
                acc3[j] += xr[j+3] * wd.w;
            }
        }

        // tail taps k = 540, 541, 542 (scalar LDS reads)
        {
            float w0a = w0[KLEN-3], w0b = w0[KLEN-2], w0c = w0[KLEN-1];
            float w1a = w1[KLEN-3], w1b = w1[KLEN-2], w1c = w1[KLEN-1];
            float w2a = w2[KLEN-3], w2b = w2[KLEN-2], w2c = w2[KLEN-1];
            float w3a = w3[KLEN-3], w3b = w3[KLEN-2], w3c = w3[KLEN-1];
            #pragma unroll
            for (int j = 0; j < VT; ++j) {
                float xA = xs[xoff + (KLEN-3) + j];
                float xB = xs[xoff + (KLEN-2) + j];
                float xC = xs[xoff + (KLEN-1) + j];
                acc0[j] += xA * w0a + xB * w0b + xC * w0c;
                acc1[j] += xA * w1a + xB * w1b + xC * w1c;
                acc2[j] += xA * w2a + xB * w2b + xC * w2c;
                acc3[j] += xA * w3a + xB * w3b + xC * w3c;
            }
        }

        // ---- write out [b, s, t], float4-vectorized (t0 mult of 8 -> aligned) ----
        const int s0 = sGroup * SG + sp;
        float* o = out + ((size_t)b * NSC + s0) * TLEN + t0;
        *(float4*)&o[0] = make_float4(acc0[0], acc0[1], acc0[2], acc0[3]);
        *(float4*)&o[4] = make_float4(acc0[4], acc0[5], acc0[6], acc0[7]);
        o += TLEN;
        *(float4*)&o[0] = make_float4(acc1[0], acc1[1], acc1[2], acc1[3]);
        *(float4*)&o[4] = make_float4(acc1[4], acc1[5], acc1[6], acc1[7]);
        o += TLEN;
        *(float4*)&o[0] = make_float4(acc2[0], acc2[1], acc2[2], acc2[3]);
        *(float4*)&o[4] = make_float4(acc2[4], acc2[5], acc2[6], acc2[7]);
        o += TLEN;
        *(float4*)&o[0] = make_float4(acc3[0], acc3[1], acc3[2], acc3[3]);
        *(float4*)&o[4] = make_float4(acc3[4], acc3[5], acc3[6], acc3[7]);
    }
}

extern "C" void kernel_launch(void* const* d_in, const int* in_sizes, int n_in,
                              void* d_out, int out_size, void* d_ws, size_t ws_size,
                              hipStream_t stream) {
    const float* x   = (const float*)d_in[0];   // [128, 4096] fp32
    const float* W   = (const float*)d_in[1];   // [64, 543]  fp32
    float*       out = (float*)d_out;           // [128, 64, 4096] fp32

    dim3 grid(TLEN / TTILE, NSC / SG, BATCH);   // (2, 8, 128) = 2048 blocks
    ricker_cwt_f32<<<grid, dim3(BLOCK), 0, stream>>>(x, W, out);
}

// Round 3
// 215.252 us; speedup vs baseline: 4.1741x; 4.1741x over previous
//
#include <hip/hip_runtime.h>

// RickerCWT via bf16 MFMA GEMM: out[b,s,t] = sum_k x[b, t+k-271] * W[s,k]
// B=128, T=4096, S=64, K=543 (zero-padded to 544 = 17*32).
// M = t (16/tile), N = s (16/tile), K = taps, mfma_f32_16x16x32_bf16.
// A-frag (x window) needs per-lane 16B reads at arbitrary element shifts ->
// x is staged in LDS as 8 one-element-shifted bf16 copies so every A-frag is
// an aligned ds_read_b128. Region stride 1064 elems (133*8, odd in 16B chunks)
// balances bank groups: group = (5*(m&7) + (m>>3) + q) % 8 -> 8 lanes/group.

#define TLEN  4096
#define NSC   64
#define KLEN  543
#define KPAD  544            // 17 * 32, zero-padded tap
#define PADL  271
#define BLOCK 256
#define TT    512            // t-tile per block
#define SBS   32             // scales per block
#define XT    1056           // staged x elems per copy (needs 0..1054)
#define XREG  1064           // region stride in elems (1056+8, /8 = 133 odd)
#define NCOPY 8
#define NKB   17             // K-blocks of 32

typedef __attribute__((ext_vector_type(8))) short short8;
typedef __attribute__((ext_vector_type(4))) float float4v;

__device__ __forceinline__ short f2bf(float f) {
    unsigned u = __builtin_bit_cast(unsigned, f);
    unsigned r = (u + 0x7FFFu + ((u >> 16) & 1u)) >> 16;
    return (short)r;
}

__global__ __launch_bounds__(BLOCK, 3)
void ricker_cwt_mfma(const float* __restrict__ x,
                     const float* __restrict__ W,
                     float* __restrict__ out)
{
    __shared__ __align__(16) short xsm[NCOPY * XREG];   // 17024 B
    __shared__ __align__(16) short wsm[SBS * KPAD];     // 34816 B

    const int tid    = threadIdx.x;
    const int tTile  = blockIdx.x;          // 0..7
    const int s0     = blockIdx.y * SBS;    // 0 or 32
    const int b      = blockIdx.z;          // 0..127
    const int tStart = tTile * TT;

    // ---- stage x tile (halo, zero-padded) as 8 shifted bf16 copies ----
    const float* xrow = x + (size_t)b * TLEN;
    for (int p = tid; p < XT; p += BLOCK) {
        int g = tStart - PADL + p;
        float v = (g >= 0 && g < TLEN) ? xrow[g] : 0.0f;
        short bv = f2bf(v);
        #pragma unroll
        for (int c = 0; c < NCOPY; ++c) {
            int i = p - c;                    // copy c holds x_tile[i + c] at i
            if (i >= 0 && i < XT) xsm[c * XREG + i] = bv;
        }
    }

    // ---- stage W rows s0..s0+31 as bf16, K zero-padded to 544 ----
    for (int idx = tid; idx < SBS * KPAD; idx += BLOCK) {
        int r  = idx / KPAD;
        int cc = idx - r * KPAD;
        float v = (cc < KLEN) ? W[(size_t)(s0 + r) * KLEN + cc] : 0.0f;
        wsm[idx] = f2bf(v);
    }
    __syncthreads();

    // ---- wave-level GEMM: wave = 128 t  x  32 s ----
    const int lane = tid & 63;
    const int wv   = tid >> 6;       // 0..3
    const int m    = lane & 15;      // A: row m / B: col n / D: col n
    const int q    = lane >> 4;      // quad
    const int wt0  = wv * 128;       // wave t base within block tile

    // A-frag element start S = wt0 + 16*ta + m + K0 + 8*q ; copy c = m&7 is
    // constant, offset (S - c) = wt0 + 8*(m>>3) + 8*q + 16*ta + K0 (mult of 8).
    const short* abase = &xsm[(m & 7) * XREG + 8 * (m >> 3) + 8 * q + wt0];
    // B[k][n] = W[s0 + n][k]: lane n = m reads its row along k.
    const short* bbase = &wsm[m * KPAD + 8 * q];

    float4v acc[8][2];
    #pragma unroll
    for (int ta = 0; ta < 8; ++ta) {
        #pragma unroll
        for (int sb = 0; sb < 2; ++sb) acc[ta][sb] = (float4v){0.f, 0.f, 0.f, 0.f};
    }

    for (int kb = 0; kb < NKB; ++kb) {
        const int K0 = kb * 32;
        short8 bf0 = *(const short8*)&bbase[K0];
        short8 bf1 = *(const short8*)&bbase[16 * KPAD + K0];
        #pragma unroll
        for (int ta = 0; ta < 8; ++ta) {
            short8 af = *(const short8*)&abase[16 * ta + K0];
            acc[ta][0] = __builtin_amdgcn_mfma_f32_16x16x32_bf16(af, bf0, acc[ta][0], 0, 0, 0);
            acc[ta][1] = __builtin_amdgcn_mfma_f32_16x16x32_bf16(af, bf1, acc[ta][1], 0, 0, 0);
        }
    }

    // ---- epilogue: D col = lane&15 = s offset, row = 4*q + reg = t offset ----
    const int tb = tStart + wt0 + 4 * q;     // + 16*ta + reg
    #pragma unroll
    for (int ta = 0; ta < 8; ++ta) {
        #pragma unroll
        for (int sb = 0; sb < 2; ++sb) {
            int sg = s0 + sb * 16 + m;
            float* o = out + ((size_t)b * NSC + sg) * TLEN + tb + 16 * ta;
            *(float4v*)o = acc[ta][sb];      // 4 consecutive t, 16B-aligned
        }
    }
}

extern "C" void kernel_launch(void* const* d_in, const int* in_sizes, int n_in,
                              void* d_out, int out_size, void* d_ws, size_t ws_size,
                              hipStream_t stream) {
    const float* x   = (const float*)d_in[0];   // [128, 4096] fp32
    const float* W   = (const float*)d_in[1];   // [64, 543]  fp32
    float*       out = (float*)d_out;           // [128, 64, 4096] fp32

    dim3 grid(TLEN / TT, NSC / SBS, 128);       // (8, 2, 128) = 2048 blocks
    ricker_cwt_mfma<<<grid, dim3(BLOCK), 0, stream>>>(x, W, out);
}

// Round 4
// 173.769 us; speedup vs baseline: 5.1706x; 1.2387x over previous
//
#include <hip/hip_runtime.h>

// RickerCWT via bf16 MFMA GEMM (round 4): out[b,s,t] = sum_k x[b,t+k-271]*W[s,k]
// - Pre-kernel converts W fp32 -> bf16 [64][544] (zero-padded) into d_ws.
// - Main kernel: wave tile 64t x 64s, mfma_f32_32x32x16_bf16, 2x2 frags.
//   A (sliding x window) from LDS via 8 one-element-shifted bf16 copies so
//   every A-frag is an aligned ds_read_b128; copy stride 808 elems (101*8,
//   odd 16B-chunk stride) balances bank groups: (5*(m&7)+(m>>3)+q5)%8.
// - B-frags read directly from global wbf (69.6 KB, L1/L2-resident) -> LDS
//   holds only 14.5 KB -> occupancy is VGPR-, not LDS-, limited.

#define TLEN  4096
#define NSC   64
#define KLEN  543
#define KPAD  544            // 34 * 16
#define PADL  271
#define BLOCK 256
#define TT    256            // t per block (4 waves x 64t)
#define XSRC  808            // raw staged x elems (need 0..806)
#define XLEN  800            // per-copy slots (need 0..798)
#define XREG  808            // copy stride in elems (16B-aligned, bank-balanced)
#define NKS   34             // K-steps of 16

typedef __attribute__((ext_vector_type(8)))  short  short8;
typedef __attribute__((ext_vector_type(16))) float  float16v;
typedef __attribute__((ext_vector_type(4)))  float  float4v;

__device__ __forceinline__ ushort f2bf(float f) {
    unsigned u = __builtin_bit_cast(unsigned, f);
    unsigned r = (u + 0x7FFFu + ((u >> 16) & 1u)) >> 16;
    return (ushort)r;
}

__global__ __launch_bounds__(256)
void wconv(const float* __restrict__ W, ushort* __restrict__ wbf)
{
    int idx = blockIdx.x * 256 + threadIdx.x;     // 0..34815
    int s   = idx / KPAD;
    int k   = idx - s * KPAD;
    float v = (k < KLEN) ? W[(size_t)s * KLEN + k] : 0.0f;
    wbf[idx] = f2bf(v);
}

__global__ __launch_bounds__(BLOCK, 3)
void ricker_mfma2(const float* __restrict__ x,
                  const ushort* __restrict__ wbf,
                  float* __restrict__ out)
{
    __shared__ __align__(16) ushort xraw[XSRC];
    __shared__ __align__(16) ushort xsm[8 * XREG];   // 12928 B

    const int tid    = threadIdx.x;
    const int tTile  = blockIdx.x;        // 0..15
    const int b      = blockIdx.y;        // 0..127
    const int tStart = tTile * TT;

    // ---- phase A: raw bf16 x tile (halo, zero-padded), coalesced ----
    const float* xrow = x + (size_t)b * TLEN;
    for (int i = tid; i < XSRC; i += BLOCK) {
        int g = tStart - PADL + i;
        float v = (g >= 0 && g < TLEN) ? xrow[g] : 0.0f;
        xraw[i] = f2bf(v);
    }
    __syncthreads();

    // ---- phase B: 8 shifted copies, stride-1 (conflict-free) ----
    for (int idx = tid; idx < 8 * XLEN; idx += BLOCK) {   // 6400 = 25*256
        int c = idx / XLEN;
        int i = idx - c * XLEN;
        xsm[c * XREG + i] = xraw[i + c];
    }
    __syncthreads();

    // ---- wave GEMM: 64t x 64s, mfma_f32_32x32x16_bf16, 2x2 frags ----
    const int lane = tid & 63;
    const int wv   = tid >> 6;        // 0..3
    const int n    = lane & 31;       // A row m / B col n / D col (s)
    const int q5   = lane >> 5;       // k-half
    const int wt0  = wv * 64;

    // A element = wt0 + 32*tt + m + k, k = 16*ks + 8*q5 + j; copy c = m&7,
    // slot = wt0 + 32*tt + 8*(m>>3) + 16*ks + 8*q5 (multiple of 8).
    const ushort* abase  = &xsm[(n & 7) * XREG + 8 * (n >> 3) + 8 * q5 + wt0];
    // B[k][nn] = wbf[row = 32*st + n][k]; per-lane 16B global, 16B-aligned.
    const ushort* b0base = wbf + (size_t)n * KPAD + 8 * q5;
    const ushort* b1base = b0base + 32 * KPAD;

    float16v acc00 = {0.f}, acc01 = {0.f}, acc10 = {0.f}, acc11 = {0.f};
    #pragma unroll
    for (int e = 0; e < 16; ++e) { acc00[e] = 0.f; acc01[e] = 0.f; acc10[e] = 0.f; acc11[e] = 0.f; }

    for (int ks = 0; ks < NKS; ++ks) {
        const int K0 = 16 * ks;
        short8 a0 = *(const short8*)&abase[K0];          // tt=0
        short8 a1 = *(const short8*)&abase[K0 + 32];     // tt=1
        short8 bb0 = *(const short8*)&b0base[K0];        // st=0
        short8 bb1 = *(const short8*)&b1base[K0];        // st=1
        acc00 = __builtin_amdgcn_mfma_f32_32x32x16_bf16(a0, bb0, acc00, 0, 0, 0);
        acc01 = __builtin_amdgcn_mfma_f32_32x32x16_bf16(a0, bb1, acc01, 0, 0, 0);
        acc10 = __builtin_amdgcn_mfma_f32_32x32x16_bf16(a1, bb0, acc10, 0, 0, 0);
        acc11 = __builtin_amdgcn_mfma_f32_32x32x16_bf16(a1, bb1, acc11, 0, 0, 0);
    }

    // ---- epilogue: D col = n (s), row = (reg&3) + 8*(reg>>2) + 4*q5 (t) ----
    const int tb = tStart + wt0 + 4 * q5;
    float* obase = out + (size_t)b * NSC * TLEN;
    #pragma unroll
    for (int st = 0; st < 2; ++st) {
        #pragma unroll
        for (int tt = 0; tt < 2; ++tt) {
            float16v A = (st == 0) ? (tt == 0 ? acc00 : acc10)
                                   : (tt == 0 ? acc01 : acc11);
            float* o = obase + (size_t)(32 * st + n) * TLEN + tb + 32 * tt;
            #pragma unroll
            for (int r4 = 0; r4 < 4; ++r4) {
                *(float4v*)&o[8 * r4] =
                    (float4v){A[4 * r4], A[4 * r4 + 1], A[4 * r4 + 2], A[4 * r4 + 3]};
            }
        }
    }
}

extern "C" void kernel_launch(void* const* d_in, const int* in_sizes, int n_in,
                              void* d_out, int out_size, void* d_ws, size_t ws_size,
                              hipStream_t stream) {
    const float* x   = (const float*)d_in[0];   // [128, 4096] fp32
    const float* W   = (const float*)d_in[1];   // [64, 543]  fp32
    float*       out = (float*)d_out;           // [128, 64, 4096] fp32
    ushort*      wbf = (ushort*)d_ws;           // [64, 544] bf16 (69,632 B)

    wconv<<<dim3((NSC * KPAD) / 256), dim3(256), 0, stream>>>(W, wbf);
    dim3 grid(TLEN / TT, 128);                  // (16, 128) = 2048 blocks
    ricker_mfma2<<<grid, dim3(BLOCK), 0, stream>>>(x, wbf, out);
}